// Round 10
// baseline (50.013 us; speedup 1.0000x reference)
//
#include <hip/hip_runtime.h>
#include <hip/hip_bf16.h>
#include <cmath>

#define B_SZ 4096
#define N_SZ 8192
#define D_SZ 256
#define EPS 1e-8f
// zn is stored as fp8 e4m3 scaled by 16 -> acc = 256*cos.
// exp(sim-2) with sim = 2*cos = acc/128:  exp2( acc*log2e/128 - 2*log2e )
#define EXPC 0.01127105500694503f      // log2(e)/128
#define EXPB -2.8853900817779268f      // -2*log2(e)

typedef __attribute__((ext_vector_type(4))) float f32x4;
typedef __attribute__((ext_vector_type(4))) int   i32x4;
typedef __attribute__((ext_vector_type(8))) int   i32x8;

// fp8 k-segment-transposed panel layout (1 byte/elem):
//   byte(row,k) = (row>>6)*16384 + (k>>4)*1024 + (row&63)*16 + (k&15)
// panel = 64 rows x 256 k = 16 KB. One K=128 MFMA operand (32 fp8) = two
// 16-B loads 1024 B apart.

// ---- Kernel 1: norms + pos (fp32 exact) + fp8 ZN. One wave per pair (i,i+B). ----
__global__ __launch_bounds__(256) void prep_kernel(const float* __restrict__ zi,
                                                   const float* __restrict__ zj,
                                                   char* __restrict__ znb,
                                                   float* __restrict__ pos) {
    const int wave = threadIdx.x >> 6, lane = threadIdx.x & 63;
    const int i = blockIdx.x * 4 + wave;               // 0..B-1
    float4 a = reinterpret_cast<const float4*>(zi + (size_t)i * D_SZ)[lane];
    float4 b = reinterpret_cast<const float4*>(zj + (size_t)i * D_SZ)[lane];
    float ssa = a.x * a.x + a.y * a.y + a.z * a.z + a.w * a.w;
    float ssb = b.x * b.x + b.y * b.y + b.z * b.z + b.w * b.w;
    float dab = a.x * b.x + a.y * b.y + a.z * b.z + a.w * b.w;
    #pragma unroll
    for (int off = 32; off; off >>= 1) {
        ssa += __shfl_xor(ssa, off, 64);
        ssb += __shfl_xor(ssb, off, 64);
        dab += __shfl_xor(dab, off, 64);
    }
    const float invna = 1.0f / fmaxf(sqrtf(ssa), EPS);
    const float invnb = 1.0f / fmaxf(sqrtf(ssb), EPS);
    if (lane == 0) {
        float p = dab * invna * invnb * 2.0f;
        pos[i] = p;
        pos[i + B_SZ] = p;
    }
    // lane covers k = 4*lane .. 4*lane+3; seg = lane>>2, in-seg byte = (lane&3)*4.
    const float sa = invna * 16.0f, sb = invnb * 16.0f;
    const int koff = (lane >> 2) * 1024 + (lane & 3) * 4;
    {
        int pk = __builtin_amdgcn_cvt_pk_fp8_f32(a.x * sa, a.y * sa, 0, false);
        pk     = __builtin_amdgcn_cvt_pk_fp8_f32(a.z * sa, a.w * sa, pk, true);
        *reinterpret_cast<int*>(znb + (size_t)(i >> 6) * 16384 + koff + (i & 63) * 16) = pk;
    }
    {
        const int r = i + B_SZ;
        int pk = __builtin_amdgcn_cvt_pk_fp8_f32(b.x * sb, b.y * sb, 0, false);
        pk     = __builtin_amdgcn_cvt_pk_fp8_f32(b.z * sb, b.w * sb, pk, true);
        *reinterpret_cast<int*>(znb + (size_t)(r >> 6) * 16384 + koff + (r & 63) * 16) = pk;
    }
}

// ---- Kernel 2: SYMMETRIC fp8 K=128 sim-GEMM + exp-sum, col-split tiles ----
// Tiles are 256 rows x 128 cols: (rt, c2) with c2 >= 2*rt -> 1056 blocks.
// Row-sums -> partial1[c2][row] (row in rt-tile; per row slots {2T..63}).
// Col-sums (offdiag only) -> partial2[rt][col-as-row] (per row slots {0..T-1}).
// Disjoint + complete per row; unwritten slots are never read by rowsum.
// 2-deep B prefetch (nbA/nbB) covers ~2 phases of L2 latency; acc ping-pong
// overlaps EXPSUM(f-1) with MFMA(f).
__global__ __launch_bounds__(256, 2) void simlse_kernel(const char* __restrict__ znb,
                                                        float* __restrict__ partial1,
                                                        float* __restrict__ partial2) {
    const int t = threadIdx.x;
    const int wave = t >> 6, lane = t & 63;

    // Triangular decode: blockIdx.x in [0,1056) -> (rt, c2), c2 >= 2*rt.
    int bid = blockIdx.x, rt = 0;
    #pragma unroll 1
    for (; rt < 32; ++rt) {
        int cnt = 64 - 2 * rt;
        if (bid < cnt) break;
        bid -= cnt;
    }
    const int c2 = 2 * rt + bid;                 // half-chunk 0..63 (128 cols)
    const bool offdiag = ((c2 >> 1) != rt);
    __shared__ float cs[4][128];                 // per-wave col-sums

    const int rl = lane & 15;                    // A-row / B-col within fragment
    const int kg = lane >> 4;                    // 32-elem k-block index
    const int i0 = rt * 256 + wave * 64;         // wave's first row

    // A panel: 4 rowgroups x 2 k-chunks of 128; 8 dwords (32 fp8) per frag.
    const char* ap = znb + (size_t)(rt * 4 + wave) * 16384 + rl * 16;
    i32x8 afrag[4][2];
    #pragma unroll
    for (int g = 0; g < 4; ++g)
        #pragma unroll
        for (int kc = 0; kc < 2; ++kc) {
            i32x4 lo = *reinterpret_cast<const i32x4*>(
                ap + (kc * 8 + kg * 2) * 1024 + g * 256);
            i32x4 hi = *reinterpret_cast<const i32x4*>(
                ap + (kc * 8 + kg * 2 + 1) * 1024 + g * 256);
            afrag[g][kc] = __builtin_shufflevector(lo, hi, 0, 1, 2, 3, 4, 5, 6, 7);
        }

    float s_acc[4][4];
    #pragma unroll
    for (int g = 0; g < 4; ++g)
        #pragma unroll
        for (int r = 0; r < 4; ++r) s_acc[g][r] = 0.0f;

    // B base; phase f (0..7): addr = bp0 + (f>>2)*16384 + (f&3)*256
    //   (+8192 for kc=1, +1024 for hi 16 B of the 32-elem k-block)
    const char* bp0 = znb + (size_t)c2 * 2 * 16384 + kg * 2048 + rl * 16;

    i32x4 nbA0, nbA1, nbA2, nbA3;                // loads for even phases
    i32x4 nbB0, nbB1, nbB2, nbB3;                // loads for odd phases
    i32x8 bf0, bf1;
    f32x4 accA[4], accB[4];

    #define LOAD_A(F)                                                             \
        {                                                                         \
            const char* bq = bp0 + ((F) >> 2) * 16384 + ((F) & 3) * 256;          \
            nbA0 = *reinterpret_cast<const i32x4*>(bq);                           \
            nbA1 = *reinterpret_cast<const i32x4*>(bq + 1024);                    \
            nbA2 = *reinterpret_cast<const i32x4*>(bq + 8192);                    \
            nbA3 = *reinterpret_cast<const i32x4*>(bq + 9216);                    \
        }
    #define LOAD_B(F)                                                             \
        {                                                                         \
            const char* bq = bp0 + ((F) >> 2) * 16384 + ((F) & 3) * 256;          \
            nbB0 = *reinterpret_cast<const i32x4*>(bq);                           \
            nbB1 = *reinterpret_cast<const i32x4*>(bq + 1024);                    \
            nbB2 = *reinterpret_cast<const i32x4*>(bq + 8192);                    \
            nbB3 = *reinterpret_cast<const i32x4*>(bq + 9216);                    \
        }

    #define MFMA8(ACC)                                                            \
        {                                                                         \
            _Pragma("unroll")                                                     \
            for (int g = 0; g < 4; ++g) ACC[g] = (f32x4){0.f, 0.f, 0.f, 0.f};     \
            _Pragma("unroll")                                                     \
            for (int g = 0; g < 4; ++g)                                           \
                asm("v_mfma_f32_16x16x128_f8f6f4 %0, %1, %2, %0"                  \
                    : "+v"(ACC[g]) : "v"(afrag[g][0]), "v"(bf0));                 \
            _Pragma("unroll")                                                     \
            for (int g = 0; g < 4; ++g)                                           \
                asm("v_mfma_f32_16x16x128_f8f6f4 %0, %1, %2, %0"                  \
                    : "+v"(ACC[g]) : "v"(afrag[g][1]), "v"(bf1));                 \
        }

    #define EXPSUM(ACC, F)                                                        \
        {                                                                         \
            float cthr = 0.0f;                                                    \
            _Pragma("unroll")                                                     \
            for (int g = 0; g < 4; ++g)                                           \
                _Pragma("unroll")                                                 \
                for (int r = 0; r < 4; ++r) {                                     \
                    float e = __builtin_amdgcn_exp2f(fmaf(ACC[g][r], EXPC, EXPB)); \
                    s_acc[g][r] += e;                                             \
                    cthr += e;                                                    \
                }                                                                 \
            cthr += __shfl_xor(cthr, 16, 64);                                     \
            cthr += __shfl_xor(cthr, 32, 64);                                     \
            if (offdiag && lane < 16)                                             \
                cs[wave][((F) >> 2) * 64 + ((F) & 3) * 16 + rl] = cthr;           \
        }

    // Prolog: loads for phases 0 and 1 in flight.
    LOAD_A(0);
    LOAD_B(1);
    // Phase 0: consume nbA, issue phase-2 loads into nbA.
    bf0 = __builtin_shufflevector(nbA0, nbA1, 0, 1, 2, 3, 4, 5, 6, 7);
    bf1 = __builtin_shufflevector(nbA2, nbA3, 0, 1, 2, 3, 4, 5, 6, 7);
    LOAD_A(2);
    MFMA8(accA);
    #pragma unroll 1
    for (int fo = 0; fo < 3; ++fo) {
        const int f1 = 2 * fo + 1, f2 = 2 * fo + 2;
        bf0 = __builtin_shufflevector(nbB0, nbB1, 0, 1, 2, 3, 4, 5, 6, 7);
        bf1 = __builtin_shufflevector(nbB2, nbB3, 0, 1, 2, 3, 4, 5, 6, 7);
        if (f1 + 2 < 8) LOAD_B(f1 + 2);
        MFMA8(accB);
        asm volatile("s_nop 7");
        EXPSUM(accA, f1 - 1);
        bf0 = __builtin_shufflevector(nbA0, nbA1, 0, 1, 2, 3, 4, 5, 6, 7);
        bf1 = __builtin_shufflevector(nbA2, nbA3, 0, 1, 2, 3, 4, 5, 6, 7);
        if (f2 + 2 < 8) LOAD_A(f2 + 2);
        MFMA8(accA);
        asm volatile("s_nop 7");
        EXPSUM(accB, f2 - 1);
    }
    // Phase 7: consume nbB.
    bf0 = __builtin_shufflevector(nbB0, nbB1, 0, 1, 2, 3, 4, 5, 6, 7);
    bf1 = __builtin_shufflevector(nbB2, nbB3, 0, 1, 2, 3, 4, 5, 6, 7);
    MFMA8(accB);
    asm volatile("s_nop 7");
    EXPSUM(accA, 6);
    asm volatile("s_nop 7");
    EXPSUM(accB, 7);

    // Row-sums over the 16 col-lanes (rl); rows i0 + g*16 + kg*4 + r -> slot c2.
    #pragma unroll
    for (int g = 0; g < 4; ++g)
        #pragma unroll
        for (int r = 0; r < 4; ++r) {
            float v = s_acc[g][r];
            #pragma unroll
            for (int off = 1; off < 16; off <<= 1) v += __shfl_xor(v, off, 64);
            if (rl == 0)
                partial1[(size_t)c2 * N_SZ + i0 + g * 16 + kg * 4 + r] = v;
        }

    // Col-sums: combine 4 waves, write 128 cols of half-chunk c2 -> slot rt.
    if (offdiag) {
        __syncthreads();
        if (t < 128) {
            float v = cs[0][t] + cs[1][t] + cs[2][t] + cs[3][t];
            partial2[(size_t)rt * N_SZ + c2 * 128 + t] = v;
        }
    }
    #undef LOAD_A
    #undef LOAD_B
    #undef MFMA8
    #undef EXPSUM
}

// ---- Kernel 3: per-row lse - pos, 32 block partials ----
// Row R (tile T = R>>8): valid slots are partial1[2T..63] and partial2[0..T-1].
__global__ __launch_bounds__(256) void rowsum_kernel(const float* __restrict__ partial1,
                                                     const float* __restrict__ partial2,
                                                     const float* __restrict__ pos,
                                                     float* __restrict__ bpart) {
    const int T = blockIdx.x;
    const int row = T * 256 + threadIdx.x;
    float s = -1.0f;                       // remove diagonal exp(~0)=1
    #pragma unroll 1
    for (int c2 = 2 * T; c2 < 64; ++c2) s += partial1[(size_t)c2 * N_SZ + row];
    #pragma unroll 1
    for (int r = 0; r < T; ++r) s += partial2[(size_t)r * N_SZ + row];
    float acc = 2.0f + logf(s) - pos[row];
    #pragma unroll
    for (int off = 32; off; off >>= 1) acc += __shfl_xor(acc, off, 64);
    __shared__ float w[4];
    if ((threadIdx.x & 63) == 0) w[threadIdx.x >> 6] = acc;
    __syncthreads();
    if (threadIdx.x == 0) bpart[blockIdx.x] = w[0] + w[1] + w[2] + w[3];
}

__global__ __launch_bounds__(64) void finsum_kernel(const float* __restrict__ bpart,
                                                    float* __restrict__ out) {
    float v = threadIdx.x < 32 ? bpart[threadIdx.x] : 0.0f;
    #pragma unroll
    for (int off = 32; off; off >>= 1) v += __shfl_xor(v, off, 64);
    if (threadIdx.x == 0) out[0] = v / (float)N_SZ;
}

extern "C" void kernel_launch(void* const* d_in, const int* in_sizes, int n_in,
                              void* d_out, int out_size, void* d_ws, size_t ws_size,
                              hipStream_t stream) {
    const float* zi = (const float*)d_in[0];
    const float* zj = (const float*)d_in[1];

    char* ws = (char*)d_ws;
    char* znb       = ws;                                     // 2 MB fp8 k-seg layout
    float* pos      = (float*)(ws + 2097152);                 // 32 KB
    float* partial1 = (float*)(ws + 2097152 + 32768);         // 64*8192*4 = 2 MB
    float* partial2 = (float*)(ws + 2097152 + 32768 + 2097152);   // 32*8192*4 = 1 MB
    float* bpart    = (float*)(ws + 2097152 + 32768 + 2097152 + 1048576); // 128 B
    float* out = (float*)d_out;

    prep_kernel<<<B_SZ / 4, 256, 0, stream>>>(zi, zj, znb, pos);
    simlse_kernel<<<1056, 256, 0, stream>>>(znb, partial1, partial2);
    rowsum_kernel<<<32, 256, 0, stream>>>(partial1, partial2, pos, bpart);
    finsum_kernel<<<1, 64, 0, stream>>>(bpart, out);
}

// Round 11
// 33.579 us; speedup vs baseline: 1.4894x; 1.4894x over previous
//
#include <hip/hip_runtime.h>
#include <hip/hip_bf16.h>
#include <cmath>

#define B_SZ 4096
#define N_SZ 8192
#define D_SZ 256
#define EPS 1e-8f
// zn is stored as fp8 e4m3 scaled by 16 -> acc = 256*cos.
// exp(sim-2) with sim = 2*cos = acc/128:  exp2( acc*log2e/128 - 2*log2e )
#define EXPC 0.01127105500694503f      // log2(e)/128
#define EXPB -2.8853900817779268f      // -2*log2(e)

typedef __attribute__((ext_vector_type(4))) float f32x4;
typedef __attribute__((ext_vector_type(4))) int   i32x4;
typedef __attribute__((ext_vector_type(8))) int   i32x8;

// fp8 k-segment-transposed panel layout (1 byte/elem):
//   byte(row,k) = (row>>6)*16384 + (k>>4)*1024 + (row&63)*16 + (k&15)
// panel = 64 rows x 256 k = 16 KB. One K=128 MFMA operand (32 fp8) = two
// 16-B loads 1024 B apart.

// ---- Kernel 1: norms + pos (fp32 exact) + fp8 ZN. One wave per pair (i,i+B). ----
__global__ __launch_bounds__(256) void prep_kernel(const float* __restrict__ zi,
                                                   const float* __restrict__ zj,
                                                   char* __restrict__ znb,
                                                   float* __restrict__ pos) {
    const int wave = threadIdx.x >> 6, lane = threadIdx.x & 63;
    const int i = blockIdx.x * 4 + wave;               // 0..B-1
    float4 a = reinterpret_cast<const float4*>(zi + (size_t)i * D_SZ)[lane];
    float4 b = reinterpret_cast<const float4*>(zj + (size_t)i * D_SZ)[lane];
    float ssa = a.x * a.x + a.y * a.y + a.z * a.z + a.w * a.w;
    float ssb = b.x * b.x + b.y * b.y + b.z * b.z + b.w * b.w;
    float dab = a.x * b.x + a.y * b.y + a.z * b.z + a.w * b.w;
    #pragma unroll
    for (int off = 32; off; off >>= 1) {
        ssa += __shfl_xor(ssa, off, 64);
        ssb += __shfl_xor(ssb, off, 64);
        dab += __shfl_xor(dab, off, 64);
    }
    const float invna = 1.0f / fmaxf(sqrtf(ssa), EPS);
    const float invnb = 1.0f / fmaxf(sqrtf(ssb), EPS);
    if (lane == 0) {
        float p = dab * invna * invnb * 2.0f;
        pos[i] = p;
        pos[i + B_SZ] = p;
    }
    // lane covers k = 4*lane .. 4*lane+3; seg = lane>>2, in-seg byte = (lane&3)*4.
    const float sa = invna * 16.0f, sb = invnb * 16.0f;
    const int koff = (lane >> 2) * 1024 + (lane & 3) * 4;
    {
        int pk = __builtin_amdgcn_cvt_pk_fp8_f32(a.x * sa, a.y * sa, 0, false);
        pk     = __builtin_amdgcn_cvt_pk_fp8_f32(a.z * sa, a.w * sa, pk, true);
        *reinterpret_cast<int*>(znb + (size_t)(i >> 6) * 16384 + koff + (i & 63) * 16) = pk;
    }
    {
        const int r = i + B_SZ;
        int pk = __builtin_amdgcn_cvt_pk_fp8_f32(b.x * sb, b.y * sb, 0, false);
        pk     = __builtin_amdgcn_cvt_pk_fp8_f32(b.z * sb, b.w * sb, pk, true);
        *reinterpret_cast<int*>(znb + (size_t)(r >> 6) * 16384 + koff + (r & 63) * 16) = pk;
    }
}

// ---- Kernel 2: SYMMETRIC fp8 K=128 sim-GEMM + exp-sum, 8-wave high-occupancy ----
// Compact triangular grid: 528 blocks of 512 threads (8 waves), tiles 256x256.
// Wave w owns 32 rows (M_w=32): afrag 32 VGPRs -> ~110 total -> 4 waves/SIMD
// (launch_bounds(512,4), VGPR cap 128) = 2x the TLP of r9. Row-sums -> slot
// chunk; col-sums (offdiag) -> slot rt; per row slots {t..31} u {0..t-1} are
// disjoint+complete (r9-proven bookkeeping). Acc ping-pong + 1-deep prefetch.
__global__ __launch_bounds__(512, 4) void simlse_kernel(const char* __restrict__ znb,
                                                        float* __restrict__ partial) {
    const int t = threadIdx.x;
    const int wave = t >> 6, lane = t & 63;

    // Triangular decode: blockIdx.x in [0,528) -> (rt, chunk), rt <= chunk.
    int bid = blockIdx.x, rt = 0;
    #pragma unroll 1
    for (; rt < 32; ++rt) {
        int cnt = 32 - rt;
        if (bid < cnt) break;
        bid -= cnt;
    }
    const int chunk = rt + bid;
    const bool offdiag = (rt != chunk);
    __shared__ float cs[8][256];                 // per-wave col-sums

    const int rl = lane & 15;                    // A-row / B-col within fragment
    const int kg = lane >> 4;                    // 32-elem k-block index
    const int i0 = rt * 256 + wave * 32;         // wave's first row

    // A panel: 2 rowgroups x 2 k-chunks of 128; 8 dwords (32 fp8) per frag.
    const char* ap = znb + (size_t)(rt * 4 + (wave >> 1)) * 16384 +
                     (wave & 1) * 512 + rl * 16;
    i32x8 afrag[2][2];
    #pragma unroll
    for (int g = 0; g < 2; ++g)
        #pragma unroll
        for (int kc = 0; kc < 2; ++kc) {
            i32x4 lo = *reinterpret_cast<const i32x4*>(
                ap + (kc * 8 + kg * 2) * 1024 + g * 256);
            i32x4 hi = *reinterpret_cast<const i32x4*>(
                ap + (kc * 8 + kg * 2 + 1) * 1024 + g * 256);
            afrag[g][kc] = __builtin_shufflevector(lo, hi, 0, 1, 2, 3, 4, 5, 6, 7);
        }

    float s_acc[2][4];
    #pragma unroll
    for (int g = 0; g < 2; ++g)
        #pragma unroll
        for (int r = 0; r < 4; ++r) s_acc[g][r] = 0.0f;

    // B base; phase f (0..15): addr = bp0 + (f>>2)*16384 + (f&3)*256
    //   (+8192 for kc=1, +1024 for hi 16 B of the 32-elem k-block)
    const char* bp0 = znb + (size_t)chunk * 4 * 16384 + kg * 2048 + rl * 16;

    i32x4 nb0 = *reinterpret_cast<const i32x4*>(bp0);
    i32x4 nb1 = *reinterpret_cast<const i32x4*>(bp0 + 1024);
    i32x4 nb2 = *reinterpret_cast<const i32x4*>(bp0 + 8192);
    i32x4 nb3 = *reinterpret_cast<const i32x4*>(bp0 + 9216);

    i32x8 bf0, bf1;
    f32x4 accA[2], accB[2];

    #define PREP_B(F)                                                             \
        {                                                                         \
            bf0 = __builtin_shufflevector(nb0, nb1, 0, 1, 2, 3, 4, 5, 6, 7);      \
            bf1 = __builtin_shufflevector(nb2, nb3, 0, 1, 2, 3, 4, 5, 6, 7);      \
            if ((F) < 15) {                                                       \
                const char* bq = bp0 + (((F) + 1) >> 2) * 16384 +                 \
                                 (((F) + 1) & 3) * 256;                           \
                nb0 = *reinterpret_cast<const i32x4*>(bq);                        \
                nb1 = *reinterpret_cast<const i32x4*>(bq + 1024);                 \
                nb2 = *reinterpret_cast<const i32x4*>(bq + 8192);                 \
                nb3 = *reinterpret_cast<const i32x4*>(bq + 9216);                 \
            }                                                                     \
        }

    #define MFMA4(ACC)                                                            \
        {                                                                         \
            _Pragma("unroll")                                                     \
            for (int g = 0; g < 2; ++g) ACC[g] = (f32x4){0.f, 0.f, 0.f, 0.f};     \
            _Pragma("unroll")                                                     \
            for (int g = 0; g < 2; ++g)                                           \
                asm("v_mfma_f32_16x16x128_f8f6f4 %0, %1, %2, %0"                  \
                    : "+v"(ACC[g]) : "v"(afrag[g][0]), "v"(bf0));                 \
            _Pragma("unroll")                                                     \
            for (int g = 0; g < 2; ++g)                                           \
                asm("v_mfma_f32_16x16x128_f8f6f4 %0, %1, %2, %0"                  \
                    : "+v"(ACC[g]) : "v"(afrag[g][1]), "v"(bf1));                 \
        }

    #define EXPSUM(ACC, F)                                                        \
        {                                                                         \
            float cthr = 0.0f;                                                    \
            _Pragma("unroll")                                                     \
            for (int g = 0; g < 2; ++g)                                           \
                _Pragma("unroll")                                                 \
                for (int r = 0; r < 4; ++r) {                                     \
                    float e = __builtin_amdgcn_exp2f(fmaf(ACC[g][r], EXPC, EXPB)); \
                    s_acc[g][r] += e;                                             \
                    cthr += e;                                                    \
                }                                                                 \
            cthr += __shfl_xor(cthr, 16, 64);                                     \
            cthr += __shfl_xor(cthr, 32, 64);                                     \
            if (offdiag && lane < 16)                                             \
                cs[wave][((F) >> 2) * 64 + ((F) & 3) * 16 + rl] = cthr;           \
        }

    // Pipelined: MFMA(phase f) overlaps EXPSUM(phase f-1).
    PREP_B(0);
    MFMA4(accA);
    #pragma unroll 1
    for (int fo = 0; fo < 7; ++fo) {
        const int f1 = 2 * fo + 1, f2 = 2 * fo + 2;
        PREP_B(f1); MFMA4(accB);
        asm volatile("s_nop 7");
        EXPSUM(accA, f1 - 1);
        PREP_B(f2); MFMA4(accA);
        asm volatile("s_nop 7");
        EXPSUM(accB, f2 - 1);
    }
    PREP_B(15); MFMA4(accB);
    asm volatile("s_nop 7");
    EXPSUM(accA, 14);
    asm volatile("s_nop 7");
    EXPSUM(accB, 15);

    // Row-sums over the 16 col-lanes (rl); rows i0 + g*16 + kg*4 + r -> slot chunk.
    #pragma unroll
    for (int g = 0; g < 2; ++g)
        #pragma unroll
        for (int r = 0; r < 4; ++r) {
            float v = s_acc[g][r];
            #pragma unroll
            for (int off = 1; off < 16; off <<= 1) v += __shfl_xor(v, off, 64);
            if (rl == 0)
                partial[chunk * N_SZ + i0 + g * 16 + kg * 4 + r] = v;
        }

    // Col-sums: combine 8 waves, write 256 cols of the chunk-tile -> slot rt.
    if (offdiag) {
        __syncthreads();
        if (t < 256) {
            float v = 0.0f;
            #pragma unroll
            for (int w = 0; w < 8; ++w) v += cs[w][t];
            partial[rt * N_SZ + chunk * 256 + t] = v;
        }
    }
    #undef PREP_B
    #undef MFMA4
    #undef EXPSUM
}

// ---- Kernel 3: per-row lse - pos, 32 block partials ----
__global__ __launch_bounds__(256) void rowsum_kernel(const float* __restrict__ partial,
                                                     const float* __restrict__ pos,
                                                     float* __restrict__ bpart) {
    const int row = blockIdx.x * 256 + threadIdx.x;
    float s = -1.0f;                       // remove diagonal exp(~0)=1
    #pragma unroll
    for (int c = 0; c < 32; ++c) s += partial[c * N_SZ + row];
    float acc = 2.0f + logf(s) - pos[row];
    #pragma unroll
    for (int off = 32; off; off >>= 1) acc += __shfl_xor(acc, off, 64);
    __shared__ float w[4];
    if ((threadIdx.x & 63) == 0) w[threadIdx.x >> 6] = acc;
    __syncthreads();
    if (threadIdx.x == 0) bpart[blockIdx.x] = w[0] + w[1] + w[2] + w[3];
}

__global__ __launch_bounds__(64) void finsum_kernel(const float* __restrict__ bpart,
                                                    float* __restrict__ out) {
    float v = threadIdx.x < 32 ? bpart[threadIdx.x] : 0.0f;
    #pragma unroll
    for (int off = 32; off; off >>= 1) v += __shfl_xor(v, off, 64);
    if (threadIdx.x == 0) out[0] = v / (float)N_SZ;
}

extern "C" void kernel_launch(void* const* d_in, const int* in_sizes, int n_in,
                              void* d_out, int out_size, void* d_ws, size_t ws_size,
                              hipStream_t stream) {
    const float* zi = (const float*)d_in[0];
    const float* zj = (const float*)d_in[1];

    char* ws = (char*)d_ws;
    char* znb      = ws;                                   // 2 MB fp8 k-seg layout
    float* pos     = (float*)(ws + 2097152);               // 32 KB
    float* partial = (float*)(ws + 2097152 + 32768);       // 32*8192*4 = 1 MB
    float* bpart   = (float*)(ws + 2097152 + 32768 + 1048576); // 128 B
    float* out = (float*)d_out;

    prep_kernel<<<B_SZ / 4, 256, 0, stream>>>(zi, zj, znb, pos);
    simlse_kernel<<<528, 512, 0, stream>>>(znb, partial);
    rowsum_kernel<<<32, 256, 0, stream>>>(partial, pos, bpart);
    finsum_kernel<<<1, 64, 0, stream>>>(bpart, out);
}

// Round 12
// 32.921 us; speedup vs baseline: 1.5192x; 1.0200x over previous
//
#include <hip/hip_runtime.h>
#include <hip/hip_bf16.h>
#include <cmath>

#define B_SZ 4096
#define N_SZ 8192
#define D_SZ 256
#define EPS 1e-8f
// zn is stored as fp8 e4m3 scaled by 16 -> acc = 256*cos.
// exp(sim-2) with sim = 2*cos = acc/128:  exp2( acc*log2e/128 - 2*log2e )
#define EXPC 0.01127105500694503f      // log2(e)/128
#define EXPB -2.8853900817779268f      // -2*log2(e)

typedef __attribute__((ext_vector_type(4))) float f32x4;
typedef __attribute__((ext_vector_type(4))) int   i32x4;
typedef __attribute__((ext_vector_type(8))) int   i32x8;

__device__ __forceinline__ void dma16(const void* g, void* l) {
    __builtin_amdgcn_global_load_lds(
        (const __attribute__((address_space(1))) unsigned int*)g,
        (__attribute__((address_space(3))) unsigned int*)l, 16, 0, 0);
}

// fp8 k-segment-transposed panel layout (1 byte/elem):
//   byte(row,k) = (row>>6)*16384 + (k>>4)*1024 + (row&63)*16 + (k&15)
// panel = 64 rows x 256 k = 16 KB. One K=128 MFMA operand (32 fp8) = two
// 16-B loads 1024 B apart.

// ---- Kernel 1: norms + pos (fp32 exact) + fp8 ZN + zero the reduce ctrl. ----
__global__ __launch_bounds__(256) void prep_kernel(const float* __restrict__ zi,
                                                   const float* __restrict__ zj,
                                                   char* __restrict__ znb,
                                                   float* __restrict__ pos,
                                                   float* __restrict__ accf,
                                                   unsigned* __restrict__ counter) {
    if (blockIdx.x == 0 && threadIdx.x == 0) { *accf = 0.0f; *counter = 0u; }
    const int wave = threadIdx.x >> 6, lane = threadIdx.x & 63;
    const int i = blockIdx.x * 4 + wave;               // 0..B-1
    float4 a = reinterpret_cast<const float4*>(zi + (size_t)i * D_SZ)[lane];
    float4 b = reinterpret_cast<const float4*>(zj + (size_t)i * D_SZ)[lane];
    float ssa = a.x * a.x + a.y * a.y + a.z * a.z + a.w * a.w;
    float ssb = b.x * b.x + b.y * b.y + b.z * b.z + b.w * b.w;
    float dab = a.x * b.x + a.y * b.y + a.z * b.z + a.w * b.w;
    #pragma unroll
    for (int off = 32; off; off >>= 1) {
        ssa += __shfl_xor(ssa, off, 64);
        ssb += __shfl_xor(ssb, off, 64);
        dab += __shfl_xor(dab, off, 64);
    }
    const float invna = 1.0f / fmaxf(sqrtf(ssa), EPS);
    const float invnb = 1.0f / fmaxf(sqrtf(ssb), EPS);
    if (lane == 0) {
        float p = dab * invna * invnb * 2.0f;
        pos[i] = p;
        pos[i + B_SZ] = p;
    }
    // lane covers k = 4*lane .. 4*lane+3; seg = lane>>2, in-seg byte = (lane&3)*4.
    const float sa = invna * 16.0f, sb = invnb * 16.0f;
    const int koff = (lane >> 2) * 1024 + (lane & 3) * 4;
    {
        int pk = __builtin_amdgcn_cvt_pk_fp8_f32(a.x * sa, a.y * sa, 0, false);
        pk     = __builtin_amdgcn_cvt_pk_fp8_f32(a.z * sa, a.w * sa, pk, true);
        *reinterpret_cast<int*>(znb + (size_t)(i >> 6) * 16384 + koff + (i & 63) * 16) = pk;
    }
    {
        const int r = i + B_SZ;
        int pk = __builtin_amdgcn_cvt_pk_fp8_f32(b.x * sb, b.y * sb, 0, false);
        pk     = __builtin_amdgcn_cvt_pk_fp8_f32(b.z * sb, b.w * sb, pk, true);
        *reinterpret_cast<int*>(znb + (size_t)(r >> 6) * 16384 + koff + (r & 63) * 16) = pk;
    }
}

// ---- Kernel 2: SYMMETRIC fp8 K=128 sim-GEMM + exp-sum, LDS-staged B ----
// 528 triangular blocks x 512 thr (8 waves, M_w=32). B panel (64 KB) staged to
// LDS ONCE per block via global_load_lds; ONE barrier; 16 phases of pure
// ds_read_b128 + MFMA + exp (no barriers/vmcnt in hot loop). Row-sums -> slot
// chunk; col-sums (offdiag) -> slot rt (r9-proven disjoint+complete bookkeeping).
__global__ __launch_bounds__(512, 4) void simlse_kernel(const char* __restrict__ znb,
                                                        float* __restrict__ partial) {
    __shared__ __attribute__((aligned(16))) char blds[65536];
    __shared__ float cs[8][256];

    const int t = threadIdx.x;
    const int wave = t >> 6, lane = t & 63;

    // Triangular decode: blockIdx.x in [0,528) -> (rt, chunk), rt <= chunk.
    int bid = blockIdx.x, rt = 0;
    #pragma unroll 1
    for (; rt < 32; ++rt) {
        int cnt = 32 - rt;
        if (bid < cnt) break;
        bid -= cnt;
    }
    const int chunk = rt + bid;
    const bool offdiag = (rt != chunk);

    const int rl = lane & 15;                    // A-row / B-col within fragment
    const int kg = lane >> 4;                    // 32-elem k-block index
    const int i0 = rt * 256 + wave * 32;         // wave's first row

    // Stage chunk's 64 KB B panel linearly: 512 thr x 8 x 16 B.
    {
        const char* gp = znb + (size_t)chunk * 65536 + t * 16;
        char* lp = blds + t * 16;
        #pragma unroll
        for (int c = 0; c < 8; ++c) dma16(gp + c * 8192, lp + c * 8192);
    }

    // A panel: 2 rowgroups x 2 k-chunks of 128 (loads overlap the DMA).
    const char* ap = znb + (size_t)(rt * 4 + (wave >> 1)) * 16384 +
                     (wave & 1) * 512 + rl * 16;
    i32x8 afrag[2][2];
    #pragma unroll
    for (int g = 0; g < 2; ++g)
        #pragma unroll
        for (int kc = 0; kc < 2; ++kc) {
            i32x4 lo = *reinterpret_cast<const i32x4*>(
                ap + (kc * 8 + kg * 2) * 1024 + g * 256);
            i32x4 hi = *reinterpret_cast<const i32x4*>(
                ap + (kc * 8 + kg * 2 + 1) * 1024 + g * 256);
            afrag[g][kc] = __builtin_shufflevector(lo, hi, 0, 1, 2, 3, 4, 5, 6, 7);
        }

    float s_acc[2][4];
    #pragma unroll
    for (int g = 0; g < 2; ++g)
        #pragma unroll
        for (int r = 0; r < 4; ++r) s_acc[g][r] = 0.0f;

    // B base in LDS; phase f (0..15): addr = bp0 + (f>>2)*16384 + (f&3)*256
    //   (+8192 for kc=1, +1024 for hi 16 B of the 32-elem k-block)
    const char* bp0 = blds + kg * 2048 + rl * 16;

    i32x8 bf0, bf1;
    f32x4 accA[2], accB[2];

    #define PREP_B(F)                                                             \
        {                                                                         \
            const char* bq = bp0 + ((F) >> 2) * 16384 + ((F) & 3) * 256;          \
            i32x4 l0 = *reinterpret_cast<const i32x4*>(bq);                       \
            i32x4 l1 = *reinterpret_cast<const i32x4*>(bq + 1024);                \
            i32x4 l2 = *reinterpret_cast<const i32x4*>(bq + 8192);                \
            i32x4 l3 = *reinterpret_cast<const i32x4*>(bq + 9216);                \
            bf0 = __builtin_shufflevector(l0, l1, 0, 1, 2, 3, 4, 5, 6, 7);        \
            bf1 = __builtin_shufflevector(l2, l3, 0, 1, 2, 3, 4, 5, 6, 7);        \
        }

    #define MFMA4(ACC)                                                            \
        {                                                                         \
            _Pragma("unroll")                                                     \
            for (int g = 0; g < 2; ++g) ACC[g] = (f32x4){0.f, 0.f, 0.f, 0.f};     \
            _Pragma("unroll")                                                     \
            for (int g = 0; g < 2; ++g)                                           \
                asm("v_mfma_f32_16x16x128_f8f6f4 %0, %1, %2, %0"                  \
                    : "+v"(ACC[g]) : "v"(afrag[g][0]), "v"(bf0));                 \
            _Pragma("unroll")                                                     \
            for (int g = 0; g < 2; ++g)                                           \
                asm("v_mfma_f32_16x16x128_f8f6f4 %0, %1, %2, %0"                  \
                    : "+v"(ACC[g]) : "v"(afrag[g][1]), "v"(bf1));                 \
        }

    #define EXPSUM(ACC, F)                                                        \
        {                                                                         \
            float cthr = 0.0f;                                                    \
            _Pragma("unroll")                                                     \
            for (int g = 0; g < 2; ++g)                                           \
                _Pragma("unroll")                                                 \
                for (int r = 0; r < 4; ++r) {                                     \
                    float e = __builtin_amdgcn_exp2f(fmaf(ACC[g][r], EXPC, EXPB)); \
                    s_acc[g][r] += e;                                             \
                    cthr += e;                                                    \
                }                                                                 \
            cthr += __shfl_xor(cthr, 16, 64);                                     \
            cthr += __shfl_xor(cthr, 32, 64);                                     \
            if (offdiag && lane < 16)                                             \
                cs[wave][((F) >> 2) * 64 + ((F) & 3) * 16 + rl] = cthr;           \
        }

    __syncthreads();                       // B panel landed (drains vmcnt)

    // Pipelined: MFMA(phase f) overlaps EXPSUM(phase f-1).
    PREP_B(0);
    MFMA4(accA);
    #pragma unroll 1
    for (int fo = 0; fo < 7; ++fo) {
        const int f1 = 2 * fo + 1, f2 = 2 * fo + 2;
        PREP_B(f1); MFMA4(accB);
        asm volatile("s_nop 7");
        EXPSUM(accA, f1 - 1);
        PREP_B(f2); MFMA4(accA);
        asm volatile("s_nop 7");
        EXPSUM(accB, f2 - 1);
    }
    PREP_B(15); MFMA4(accB);
    asm volatile("s_nop 7");
    EXPSUM(accA, 14);
    asm volatile("s_nop 7");
    EXPSUM(accB, 15);

    // Row-sums over the 16 col-lanes (rl); rows i0 + g*16 + kg*4 + r -> slot chunk.
    #pragma unroll
    for (int g = 0; g < 2; ++g)
        #pragma unroll
        for (int r = 0; r < 4; ++r) {
            float v = s_acc[g][r];
            #pragma unroll
            for (int off = 1; off < 16; off <<= 1) v += __shfl_xor(v, off, 64);
            if (rl == 0)
                partial[chunk * N_SZ + i0 + g * 16 + kg * 4 + r] = v;
        }

    // Col-sums: combine 8 waves, write 256 cols of the chunk-tile -> slot rt.
    if (offdiag) {
        __syncthreads();
        if (t < 256) {
            float v = 0.0f;
            #pragma unroll
            for (int w = 0; w < 8; ++w) v += cs[w][t];
            partial[rt * N_SZ + chunk * 256 + t] = v;
        }
    }
    #undef PREP_B
    #undef MFMA4
    #undef EXPSUM
}

// ---- Kernel 3: per-row lse - pos; device-scope atomic final reduce ----
// Last block (counter==31) writes out[0]; accf/counter zeroed by prep each call.
__global__ __launch_bounds__(256) void rowsum_kernel(const float* __restrict__ partial,
                                                     const float* __restrict__ pos,
                                                     float* __restrict__ accf,
                                                     unsigned* __restrict__ counter,
                                                     float* __restrict__ out) {
    const int row = blockIdx.x * 256 + threadIdx.x;
    float s = -1.0f;                       // remove diagonal exp(~0)=1
    #pragma unroll
    for (int c = 0; c < 32; ++c) s += partial[c * N_SZ + row];
    float acc = 2.0f + logf(s) - pos[row];
    #pragma unroll
    for (int off = 32; off; off >>= 1) acc += __shfl_xor(acc, off, 64);
    __shared__ float w[4];
    if ((threadIdx.x & 63) == 0) w[threadIdx.x >> 6] = acc;
    __syncthreads();
    if (threadIdx.x == 0) {
        atomicAdd(accf, w[0] + w[1] + w[2] + w[3]);
        __threadfence();
        unsigned old = atomicAdd(counter, 1u);
        if (old == 31u) {
            float tot = atomicAdd(accf, 0.0f);     // atomic read of final sum
            out[0] = tot / (float)N_SZ;
        }
    }
}

extern "C" void kernel_launch(void* const* d_in, const int* in_sizes, int n_in,
                              void* d_out, int out_size, void* d_ws, size_t ws_size,
                              hipStream_t stream) {
    const float* zi = (const float*)d_in[0];
    const float* zj = (const float*)d_in[1];

    char* ws = (char*)d_ws;
    char* znb       = ws;                                   // 2 MB fp8 k-seg layout
    float* pos      = (float*)(ws + 2097152);               // 32 KB
    float* partial  = (float*)(ws + 2097152 + 32768);       // 32*8192*4 = 1 MB
    float* accf     = (float*)(ws + 2097152 + 32768 + 1048576);
    unsigned* counter = (unsigned*)(ws + 2097152 + 32768 + 1048576 + 4);
    float* out = (float*)d_out;

    prep_kernel<<<B_SZ / 4, 256, 0, stream>>>(zi, zj, znb, pos, accf, counter);
    simlse_kernel<<<528, 512, 0, stream>>>(znb, partial);
    rowsum_kernel<<<32, 256, 0, stream>>>(partial, pos, accf, counter, out);
}